// Round 4
// baseline (207.289 us; speedup 1.0000x reference)
//
#include <hip/hip_runtime.h>

// Problem constants (from reference): S=7, B=2, C=20, N=30, batch=16384
#define NCH 30
#define RANK_LIMIT 49          // S*S
#define L_COORD 5.0f
#define L_NOOBJ 0.5f

// Exact-cover persistent geometry: 802816 rows * 30 / 4 = 6,021,120 float4
// per array = 1960 blocks * 256 threads * UNROLL 4 * OUTER 3 exactly.
// R3 showed 15 vs 30 waves/CU is perf-neutral (not latency-bound); keep the
// 1960-block shape. R4 change: drop the nontemporal hint — NT reads bypass
// L2/L3 allocation and forgo Infinity-Cache hits + TCC burst merge; this is
// the last single-variable difference vs the 6.3 TB/s reference streams.
#define NB 1960
#define UNROLL 4
#define OUTER 3
#define CHUNK (256 * UNROLL)         // float4s per block per iteration
#define NBLK_TOTAL (NB + 1)          // + 1 dedicated bbox block (blockIdx 0)

typedef float vfloat4 __attribute__((ext_vector_type(4)));

// Block-reduce a per-thread value into thread 0 (others get 0).
__device__ inline float block_reduce(float v) {
    #pragma unroll
    for (int off = 32; off > 0; off >>= 1)
        v += __shfl_down(v, off, 64);
    __shared__ float s[4];
    int lane = threadIdx.x & 63, wid = threadIdx.x >> 6;
    if (lane == 0) s[wid] = v;
    __syncthreads();
    return (threadIdx.x == 0) ? (s[0] + s[1] + s[2] + s[3]) : 0.0f;
}

// ---------------------------------------------------------------------------
// Per-row "selected" bbox loss — faithful port of the reference including its
// bugs: x2y2 built from the already-transformed xy; lambda_coord only on the
// x / sqrt(w) terms; selected loss sums l1+l2+l3+IoU; argmax keeps first max.
// ---------------------------------------------------------------------------
__device__ inline float sel_loss(const float* __restrict__ p,
                                 const float* __restrict__ t, int row) {
    const float invS = 1.0f / 7.0f;
    int b0 = row * NCH;
    float tot0 = 0.f, tot1 = 0.f, iou0 = 0.f, iou1 = 0.f;
    #pragma unroll
    for (int j = 0; j < 2; ++j) {
        int o = b0 + 5 * j;
        float px = p[o + 0], py = p[o + 1], pw = p[o + 2], ph = p[o + 3], pc = p[o + 4];
        float tx = t[o + 0], ty = t[o + 1], tw = t[o + 2], th = t[o + 3], tc = t[o + 4];
        float pxy0 = px * invS - 0.5f * pw;
        float pxy1 = py * invS - 0.5f * ph;
        float p2x  = pxy0 * invS + 0.5f * pw;
        float p2y  = pxy1 * invS + 0.5f * ph;
        float txy0 = tx * invS - 0.5f * tw;
        float txy1 = ty * invS - 0.5f * th;
        float t2x  = txy0 * invS + 0.5f * tw;
        float t2y  = txy1 * invS + 0.5f * th;
        float d0 = txy0 - pxy0, d1 = txy1 - pxy1;
        float l1 = L_COORD * d0 * d0 + d1 * d1;
        float s0 = sqrtf(t2x) - sqrtf(p2x);
        float s1 = sqrtf(t2y) - sqrtf(p2y);
        float l2 = L_COORD * s0 * s0 + s1 * s1;
        float dc = tc - pc;
        float l3 = dc * dc;
        float ltx = fmaxf(pxy0, txy0), lty = fmaxf(pxy1, txy1);
        float rbx = fminf(p2x, t2x),   rby = fminf(p2y, t2y);
        float wx  = fmaxf(rbx - ltx, 0.0f);
        float wy  = fmaxf(rby - lty, 0.0f);
        float inter  = wx * wy;
        float area_p = (p2x - pxy0) * (p2y - pxy1);
        float area_t = (t2x - txy0) * (t2y - txy1);
        float io = inter / (area_p + area_t - inter);
        float tt = l1 + l2 + l3 + io;
        if (j == 0) { iou0 = io; tot0 = tt; }
        else        { iou1 = io; tot1 = tt; }
    }
    return (iou1 > iou0) ? tot1 : tot0;   // argmax keeps FIRST max
}

// ---------------------------------------------------------------------------
// Fused main kernel, persistent-streamer variant — CACHED loads (no nt).
// Block 0: ordered ballot-scan bbox loss (first dispatch round, overlapped).
// Blocks [1, NB]: grid-stride loop, OUTER iterations of UNROLL=4 plain
// float4 loads from each array. Contiguous float4 is the only pattern this
// memory system runs at full rate (R1/R2: 64B-granular sparse streams
// plateau at 1.3 TB/s regardless of lane mapping). All blocks end with ONE
// PLAIN STORE of their partial (R7: fence+atomic combine serializes L2).
//
// Channel decode (60-float / 15-float4 two-row groups, pair=i/15, k=i%15):
//   k==1: even-row ch4..7  -> t4 = vt.x (gate+term), p4 = vp.x
//   k==2: even-row ch8..11 -> t9 = vt.y, p9 = vp.y, gate t4 = lane(l-1) vt.x
//   k==8: odd-row  ch2..5  -> t4 = vt.z (gate+term), p4 = vp.z
//   k==9: odd-row  ch6..9  -> t9 = vt.w, p9 = vp.w, gate t4 = lane(l-1) vt.z
// ---------------------------------------------------------------------------
__global__ __launch_bounds__(256) void yolo_kernel(const vfloat4* __restrict__ pv,
                                                   const vfloat4* __restrict__ tv,
                                                   const float* __restrict__ ps,
                                                   const float* __restrict__ ts,
                                                   float* __restrict__ partials,
                                                   int M) {
    const int tid  = threadIdx.x;
    const int lane = tid & 63;

    if (blockIdx.x != 0) {
        // ---- persistent noobj streaming path ----
        const int bid = blockIdx.x - 1;          // 0..NB-1
        float s_acc = 0.0f;
        int base = bid * CHUNK + tid;
        const int step = NB * CHUNK;             // 2,007,040 float4s

        for (int outer = 0; outer < OUTER; ++outer, base += step) {
            vfloat4 vp[UNROLL], vt[UNROLL];
            #pragma unroll
            for (int u = 0; u < UNROLL; ++u) {
                int i = base + u * 256;
                vp[u] = pv[i];                   // plain cached load
                vt[u] = tv[i];
            }

            #pragma unroll
            for (int u = 0; u < UNROLL; ++u) {
                int i = base + u * 256;
                int pair = i / 15;               // magic-mul
                int k = i - pair * 15;

                float gx = __shfl_up(vt[u].x, 1, 64);
                float gz = __shfl_up(vt[u].z, 1, 64);
                if (lane == 0) {                 // wave-boundary fallback (rare)
                    if (k == 2) gx = ts[pair * 60 + 4];
                    if (k == 9) gz = ts[pair * 60 + 34];
                }

                float d1 = vp[u].x - vt[u].x;
                float d2 = vp[u].y - vt[u].y;
                float d8 = vp[u].z - vt[u].z;
                float d9 = vp[u].w - vt[u].w;

                float c1 = (!(vt[u].x > 0.0f)) ? d1 * d1 : 0.0f;
                float c2 = (!(gx      > 0.0f)) ? d2 * d2 : 0.0f;
                float c8 = (!(vt[u].z > 0.0f)) ? d8 * d8 : 0.0f;
                float c9 = (!(gz      > 0.0f)) ? d9 * d9 : 0.0f;

                s_acc += (k == 1) ? c1 : (k == 2) ? c2 : (k == 8) ? c8
                       : (k == 9) ? c9 : 0.0f;
            }
        }

        float part = block_reduce(s_acc);
        if (tid == 0) partials[blockIdx.x] = L_NOOBJ * part;  // plain store
    } else {
        // ---- bbox ordered-scan path (block 0, first dispatch round) ----
        __shared__ int s_wcnt[4];
        __shared__ int s_base;
        if (tid == 0) s_base = 0;
        __syncthreads();

        float local = 0.0f;
        for (int start = 0; start < M; start += 256) {
            int row = start + tid;
            bool obj = false;
            if (row < M) obj = ts[row * NCH + 4] > 0.0f;

            unsigned long long mask = __ballot(obj);
            int wid = tid >> 6;
            if (lane == 0) s_wcnt[wid] = __popcll(mask);
            __syncthreads();

            int base = s_base;
            int off = 0;
            for (int w = 0; w < wid; ++w) off += s_wcnt[w];
            int rank = base + off + __popcll(mask & ((1ULL << lane) - 1ULL));
            if (obj && rank < RANK_LIMIT) local += sel_loss(ps, ts, row);
            __syncthreads();

            if (tid == 0)
                s_base = base + s_wcnt[0] + s_wcnt[1] + s_wcnt[2] + s_wcnt[3];
            __syncthreads();
            if (s_base >= RANK_LIMIT) break;   // uniform exit
        }

        float part = block_reduce(local);
        if (tid == 0) partials[0] = part;      // plain store
    }
}

// ---------------------------------------------------------------------------
// Tiny finish kernel: sum the NB+1 partials (all already scaled) -> out[0].
// ---------------------------------------------------------------------------
__global__ __launch_bounds__(256) void sum_kernel(const float* __restrict__ partials,
                                                  float* __restrict__ out) {
    float v = 0.0f;
    for (int i = threadIdx.x; i < NBLK_TOTAL; i += 256)
        v += partials[i];
    float tot = block_reduce(v);
    if (threadIdx.x == 0) out[0] = tot;
}

extern "C" void kernel_launch(void* const* d_in, const int* in_sizes, int n_in,
                              void* d_out, int out_size, void* d_ws, size_t ws_size,
                              hipStream_t stream) {
    const float* pred = (const float*)d_in[0];
    const float* targ = (const float*)d_in[1];
    float* out = (float*)d_out;
    float* partials = (float*)d_ws;      // NB+1 floats; all written before read

    int M = in_sizes[0] / NCH;           // 802816 rows

    yolo_kernel<<<NBLK_TOTAL, 256, 0, stream>>>(
        (const vfloat4*)pred, (const vfloat4*)targ, pred, targ, partials, M);
    sum_kernel<<<1, 256, 0, stream>>>(partials, out);
}

// Round 5
// 193.646 us; speedup vs baseline: 1.0705x; 1.0705x over previous
//
#include <hip/hip_runtime.h>

// Problem constants (from reference): S=7, B=2, C=20, N=30, batch=16384
#define NCH 30
#define RANK_LIMIT 49          // S*S
#define L_COORD 5.0f
#define L_NOOBJ 0.5f

// Exact-cover persistent geometry: 802816 rows * 30 / 4 = 6,021,120 float4
// per array = 1960 blocks * 256 threads * UNROLL 4 * OUTER 3 exactly.
// Evidence ledger: occupancy 15 vs 30 waves/CU neutral (R3); sparse streams
// collapse to 1.3 TB/s (R1/R2); cached loads service misses at 1.3 TB/s vs
// nt at 3.3 TB/s (R4) -> the throttle is WHERE misses are serviced.
// R5 probe: system-scope nt reads (sc0 sc1 nt) to service misses past L2,
// on the same path the 6.7 TB/s harness fills use.
#define NB 1960
#define UNROLL 4
#define OUTER 3
#define CHUNK (256 * UNROLL)         // float4s per block per iteration
#define NBLK_TOTAL (NB + 1)          // + 1 dedicated bbox block (blockIdx 0)

typedef float vfloat4 __attribute__((ext_vector_type(4)));

// Block-reduce a per-thread value into thread 0 (others get 0).
__device__ inline float block_reduce(float v) {
    #pragma unroll
    for (int off = 32; off > 0; off >>= 1)
        v += __shfl_down(v, off, 64);
    __shared__ float s[4];
    int lane = threadIdx.x & 63, wid = threadIdx.x >> 6;
    if (lane == 0) s[wid] = v;
    __syncthreads();
    return (threadIdx.x == 0) ? (s[0] + s[1] + s[2] + s[3]) : 0.0f;
}

// ---------------------------------------------------------------------------
// Per-row "selected" bbox loss — faithful port of the reference including its
// bugs: x2y2 built from the already-transformed xy; lambda_coord only on the
// x / sqrt(w) terms; selected loss sums l1+l2+l3+IoU; argmax keeps first max.
// ---------------------------------------------------------------------------
__device__ inline float sel_loss(const float* __restrict__ p,
                                 const float* __restrict__ t, int row) {
    const float invS = 1.0f / 7.0f;
    int b0 = row * NCH;
    float tot0 = 0.f, tot1 = 0.f, iou0 = 0.f, iou1 = 0.f;
    #pragma unroll
    for (int j = 0; j < 2; ++j) {
        int o = b0 + 5 * j;
        float px = p[o + 0], py = p[o + 1], pw = p[o + 2], ph = p[o + 3], pc = p[o + 4];
        float tx = t[o + 0], ty = t[o + 1], tw = t[o + 2], th = t[o + 3], tc = t[o + 4];
        float pxy0 = px * invS - 0.5f * pw;
        float pxy1 = py * invS - 0.5f * ph;
        float p2x  = pxy0 * invS + 0.5f * pw;
        float p2y  = pxy1 * invS + 0.5f * ph;
        float txy0 = tx * invS - 0.5f * tw;
        float txy1 = ty * invS - 0.5f * th;
        float t2x  = txy0 * invS + 0.5f * tw;
        float t2y  = txy1 * invS + 0.5f * th;
        float d0 = txy0 - pxy0, d1 = txy1 - pxy1;
        float l1 = L_COORD * d0 * d0 + d1 * d1;
        float s0 = sqrtf(t2x) - sqrtf(p2x);
        float s1 = sqrtf(t2y) - sqrtf(p2y);
        float l2 = L_COORD * s0 * s0 + s1 * s1;
        float dc = tc - pc;
        float l3 = dc * dc;
        float ltx = fmaxf(pxy0, txy0), lty = fmaxf(pxy1, txy1);
        float rbx = fminf(p2x, t2x),   rby = fminf(p2y, t2y);
        float wx  = fmaxf(rbx - ltx, 0.0f);
        float wy  = fmaxf(rby - lty, 0.0f);
        float inter  = wx * wy;
        float area_p = (p2x - pxy0) * (p2y - pxy1);
        float area_t = (t2x - txy0) * (t2y - txy1);
        float io = inter / (area_p + area_t - inter);
        float tt = l1 + l2 + l3 + io;
        if (j == 0) { iou0 = io; tot0 = tt; }
        else        { iou1 = io; tot1 = tt; }
    }
    return (iou1 > iou0) ? tot1 : tot0;   // argmax keeps FIRST max
}

// ---------------------------------------------------------------------------
// Fused main kernel — persistent streamer with SYSTEM-SCOPE NT loads.
//
// The 8 loads of a round are issued from ONE asm block ending in
// s_waitcnt vmcnt(0): the data dependence on the asm outputs orders every
// consumer after the waitcnt (no rule-#18 hoisting hazard). sc0 sc1 = system
// scope (service the read past L2, off the fabric/L3/DRAM path the fills
// run at 6.7 TB/s); nt = no-allocate. R4 measured the L2-allocating path
// servicing misses at 1.3 TB/s vs nt's 3.3 — this probes the third policy.
//
// Channel decode (60-float / 15-float4 two-row groups, pair=i/15, k=i%15):
//   k==1: even-row ch4..7  -> t4 = vt.x (gate+term), p4 = vp.x
//   k==2: even-row ch8..11 -> t9 = vt.y, p9 = vp.y, gate t4 = lane(l-1) vt.x
//   k==8: odd-row  ch2..5  -> t4 = vt.z (gate+term), p4 = vp.z
//   k==9: odd-row  ch6..9  -> t9 = vt.w, p9 = vp.w, gate t4 = lane(l-1) vt.z
// ---------------------------------------------------------------------------
__global__ __launch_bounds__(256) void yolo_kernel(const vfloat4* __restrict__ pv,
                                                   const vfloat4* __restrict__ tv,
                                                   const float* __restrict__ ps,
                                                   const float* __restrict__ ts,
                                                   float* __restrict__ partials,
                                                   int M) {
    const int tid  = threadIdx.x;
    const int lane = tid & 63;

    if (blockIdx.x != 0) {
        // ---- persistent noobj streaming path ----
        const int bid = blockIdx.x - 1;          // 0..NB-1
        float s_acc = 0.0f;
        int base = bid * CHUNK + tid;
        const int step = NB * CHUNK;             // 2,007,040 float4s

        for (int outer = 0; outer < OUTER; ++outer, base += step) {
            vfloat4 vp0, vp1, vp2, vp3, vt0, vt1, vt2, vt3;
            const vfloat4* a0 = &pv[base];
            const vfloat4* a1 = &pv[base + 256];
            const vfloat4* a2 = &pv[base + 512];
            const vfloat4* a3 = &pv[base + 768];
            const vfloat4* b0 = &tv[base];
            const vfloat4* b1 = &tv[base + 256];
            const vfloat4* b2 = &tv[base + 512];
            const vfloat4* b3 = &tv[base + 768];
            asm volatile(
                "global_load_dwordx4 %0, %8,  off sc0 sc1 nt\n\t"
                "global_load_dwordx4 %1, %9,  off sc0 sc1 nt\n\t"
                "global_load_dwordx4 %2, %10, off sc0 sc1 nt\n\t"
                "global_load_dwordx4 %3, %11, off sc0 sc1 nt\n\t"
                "global_load_dwordx4 %4, %12, off sc0 sc1 nt\n\t"
                "global_load_dwordx4 %5, %13, off sc0 sc1 nt\n\t"
                "global_load_dwordx4 %6, %14, off sc0 sc1 nt\n\t"
                "global_load_dwordx4 %7, %15, off sc0 sc1 nt\n\t"
                "s_waitcnt vmcnt(0)"
                : "=&v"(vp0), "=&v"(vp1), "=&v"(vp2), "=&v"(vp3),
                  "=&v"(vt0), "=&v"(vt1), "=&v"(vt2), "=&v"(vt3)
                : "v"(a0), "v"(a1), "v"(a2), "v"(a3),
                  "v"(b0), "v"(b1), "v"(b2), "v"(b3));

            vfloat4 vp[UNROLL] = {vp0, vp1, vp2, vp3};
            vfloat4 vt[UNROLL] = {vt0, vt1, vt2, vt3};

            #pragma unroll
            for (int u = 0; u < UNROLL; ++u) {
                int i = base + u * 256;
                int pair = i / 15;               // magic-mul
                int k = i - pair * 15;

                float gx = __shfl_up(vt[u].x, 1, 64);
                float gz = __shfl_up(vt[u].z, 1, 64);
                if (lane == 0) {                 // wave-boundary fallback (rare)
                    if (k == 2) gx = ts[pair * 60 + 4];
                    if (k == 9) gz = ts[pair * 60 + 34];
                }

                float d1 = vp[u].x - vt[u].x;
                float d2 = vp[u].y - vt[u].y;
                float d8 = vp[u].z - vt[u].z;
                float d9 = vp[u].w - vt[u].w;

                float c1 = (!(vt[u].x > 0.0f)) ? d1 * d1 : 0.0f;
                float c2 = (!(gx      > 0.0f)) ? d2 * d2 : 0.0f;
                float c8 = (!(vt[u].z > 0.0f)) ? d8 * d8 : 0.0f;
                float c9 = (!(gz      > 0.0f)) ? d9 * d9 : 0.0f;

                s_acc += (k == 1) ? c1 : (k == 2) ? c2 : (k == 8) ? c8
                       : (k == 9) ? c9 : 0.0f;
            }
        }

        float part = block_reduce(s_acc);
        if (tid == 0) partials[blockIdx.x] = L_NOOBJ * part;  // plain store
    } else {
        // ---- bbox ordered-scan path (block 0, first dispatch round) ----
        __shared__ int s_wcnt[4];
        __shared__ int s_base;
        if (tid == 0) s_base = 0;
        __syncthreads();

        float local = 0.0f;
        for (int start = 0; start < M; start += 256) {
            int row = start + tid;
            bool obj = false;
            if (row < M) obj = ts[row * NCH + 4] > 0.0f;

            unsigned long long mask = __ballot(obj);
            int wid = tid >> 6;
            if (lane == 0) s_wcnt[wid] = __popcll(mask);
            __syncthreads();

            int base = s_base;
            int off = 0;
            for (int w = 0; w < wid; ++w) off += s_wcnt[w];
            int rank = base + off + __popcll(mask & ((1ULL << lane) - 1ULL));
            if (obj && rank < RANK_LIMIT) local += sel_loss(ps, ts, row);
            __syncthreads();

            if (tid == 0)
                s_base = base + s_wcnt[0] + s_wcnt[1] + s_wcnt[2] + s_wcnt[3];
            __syncthreads();
            if (s_base >= RANK_LIMIT) break;   // uniform exit
        }

        float part = block_reduce(local);
        if (tid == 0) partials[0] = part;      // plain store
    }
}

// ---------------------------------------------------------------------------
// Tiny finish kernel: sum the NB+1 partials (all already scaled) -> out[0].
// ---------------------------------------------------------------------------
__global__ __launch_bounds__(256) void sum_kernel(const float* __restrict__ partials,
                                                  float* __restrict__ out) {
    float v = 0.0f;
    for (int i = threadIdx.x; i < NBLK_TOTAL; i += 256)
        v += partials[i];
    float tot = block_reduce(v);
    if (threadIdx.x == 0) out[0] = tot;
}

extern "C" void kernel_launch(void* const* d_in, const int* in_sizes, int n_in,
                              void* d_out, int out_size, void* d_ws, size_t ws_size,
                              hipStream_t stream) {
    const float* pred = (const float*)d_in[0];
    const float* targ = (const float*)d_in[1];
    float* out = (float*)d_out;
    float* partials = (float*)d_ws;      // NB+1 floats; all written before read

    int M = in_sizes[0] / NCH;           // 802816 rows

    yolo_kernel<<<NBLK_TOTAL, 256, 0, stream>>>(
        (const vfloat4*)pred, (const vfloat4*)targ, pred, targ, partials, M);
    sum_kernel<<<1, 256, 0, stream>>>(partials, out);
}

// Round 6
// 188.851 us; speedup vs baseline: 1.0976x; 1.0254x over previous
//
#include <hip/hip_runtime.h>

// Problem constants (from reference): S=7, B=2, C=20, N=30, batch=16384
#define NCH 30
#define RANK_LIMIT 49          // S*S
#define L_COORD 5.0f
#define L_NOOBJ 0.5f

// Wave-cooperative sparse-gather geometry (R2 layout, verified absmax=0).
// Useful dwords for the noobj loss: ch4 and ch9 of every row, both arrays.
// Per 960B period (8 rows, 240 dwords): 16 useful dwords at offsets
// 60*g + {4,9,34,39}, g=0..3. Total useful per array = 2*802816 = 1,605,632
// = NB(784) * 256 threads * UPT(8). Exact cover, no bounds checks.
//
// Evidence ledger (yolo-kernel time / policy / pattern):
//   contiguous+cached 73us (R4, miss-service 1.3 TB/s) | contiguous+nt 56us
//   sparse+cached 74-75us (R1/R2 - confounded by cached-path cap, NOT by
//   sparsity) | sparse+nt: THIS KERNEL. Sparse touches 10/15 of the 64B
//   lines (128 MB vs 192.7 MB) with a monotonic pair-sharing lane layout.
#define NB 784
#define UPT 8                        // useful dwords per thread per array
#define NBLK_TOTAL (NB + 1)          // + 1 dedicated bbox block (blockIdx 0)

// Block-reduce a per-thread value into thread 0 (others get 0).
__device__ inline float block_reduce(float v) {
    #pragma unroll
    for (int off = 32; off > 0; off >>= 1)
        v += __shfl_down(v, off, 64);
    __shared__ float s[4];
    int lane = threadIdx.x & 63, wid = threadIdx.x >> 6;
    if (lane == 0) s[wid] = v;
    __syncthreads();
    return (threadIdx.x == 0) ? (s[0] + s[1] + s[2] + s[3]) : 0.0f;
}

// ---------------------------------------------------------------------------
// Per-row "selected" bbox loss — faithful port of the reference including its
// bugs: x2y2 built from the already-transformed xy; lambda_coord only on the
// x / sqrt(w) terms; selected loss sums l1+l2+l3+IoU; argmax keeps first max.
// ---------------------------------------------------------------------------
__device__ inline float sel_loss(const float* __restrict__ p,
                                 const float* __restrict__ t, int row) {
    const float invS = 1.0f / 7.0f;
    int b0 = row * NCH;
    float tot0 = 0.f, tot1 = 0.f, iou0 = 0.f, iou1 = 0.f;
    #pragma unroll
    for (int j = 0; j < 2; ++j) {
        int o = b0 + 5 * j;
        float px = p[o + 0], py = p[o + 1], pw = p[o + 2], ph = p[o + 3], pc = p[o + 4];
        float tx = t[o + 0], ty = t[o + 1], tw = t[o + 2], th = t[o + 3], tc = t[o + 4];
        float pxy0 = px * invS - 0.5f * pw;
        float pxy1 = py * invS - 0.5f * ph;
        float p2x  = pxy0 * invS + 0.5f * pw;
        float p2y  = pxy1 * invS + 0.5f * ph;
        float txy0 = tx * invS - 0.5f * tw;
        float txy1 = ty * invS - 0.5f * th;
        float t2x  = txy0 * invS + 0.5f * tw;
        float t2y  = txy1 * invS + 0.5f * th;
        float d0 = txy0 - pxy0, d1 = txy1 - pxy1;
        float l1 = L_COORD * d0 * d0 + d1 * d1;
        float s0 = sqrtf(t2x) - sqrtf(p2x);
        float s1 = sqrtf(t2y) - sqrtf(p2y);
        float l2 = L_COORD * s0 * s0 + s1 * s1;
        float dc = tc - pc;
        float l3 = dc * dc;
        float ltx = fmaxf(pxy0, txy0), lty = fmaxf(pxy1, txy1);
        float rbx = fminf(p2x, t2x),   rby = fminf(p2y, t2y);
        float wx  = fmaxf(rbx - ltx, 0.0f);
        float wy  = fmaxf(rby - lty, 0.0f);
        float inter  = wx * wy;
        float area_p = (p2x - pxy0) * (p2y - pxy1);
        float area_t = (t2x - txy0) * (t2y - txy1);
        float io = inter / (area_p + area_t - inter);
        float tt = l1 + l2 + l3 + io;
        if (j == 0) { iou0 = io; tot0 = tt; }
        else        { iou1 = io; tot1 = tt; }
    }
    return (iou1 > iou0) ? tot1 : tot0;   // argmax keeps FIRST max
}

// ---------------------------------------------------------------------------
// Fused main kernel — wave-cooperative sparse gather with NT loads.
//
// Useful-dword linear index u maps to: period q = u>>4, slot = u&15,
// dword offset = q*240 + 60*(slot>>2) + {4,9,34,39}[slot&3].
// Lane l of a wave owns u = ubase + l, so one 64-lane dword load covers
// 4 consecutive periods (10 distinct 64B lines of the 15 in that span,
// lanes pair-sharing 6 of them) and successive unrolled loads walk
// addresses monotonically: a sequential stream with 64B-granular holes.
//
// u parity = lane parity, and (2k,2k+1) = (ch4,ch9) of the SAME row, so
// the noobj gate (t_ch4 > 0) for the odd lane comes from __shfl_xor(t,1).
//
// Block 0: ordered ballot-scan bbox loss (first dispatch round, overlapped).
// All blocks end with ONE PLAIN STORE of their partial (R7: fence+atomic
// combine serializes L2).
// ---------------------------------------------------------------------------
__global__ __launch_bounds__(256) void yolo_kernel(const float* __restrict__ ps,
                                                   const float* __restrict__ ts,
                                                   float* __restrict__ partials,
                                                   int M) {
    const int tid  = threadIdx.x;
    const int lane = tid & 63;

    if (blockIdx.x != 0) {
        // ---- wave-cooperative sparse noobj path (nt loads) ----
        const int bid  = blockIdx.x - 1;         // 0..NB-1
        const int slot = tid & 15;
        const int c    = slot & 3;
        // {4,9,34,39}[c] = 4 + 5*c + 20*(c>>1)
        const int off  = 60 * (slot >> 2) + 4 + 5 * c + 20 * (c >> 1);
        // first period for this thread: bid*128 + (tid>>4); 16 slots/period
        const int base = (bid * 128 + (tid >> 4)) * 240 + off;

        float tv[UPT], pv[UPT];
        #pragma unroll
        for (int i = 0; i < UPT; ++i) {
            tv[i] = __builtin_nontemporal_load(&ts[base + i * 3840]);
            pv[i] = __builtin_nontemporal_load(&ps[base + i * 3840]);
        }

        float acc = 0.0f;
        const bool odd = (tid & 1);
        #pragma unroll
        for (int i = 0; i < UPT; ++i) {
            float g    = __shfl_xor(tv[i], 1, 64);   // partner lane's t
            float gate = odd ? g : tv[i];            // row's t_ch4 either way
            float d    = pv[i] - tv[i];
            acc += (gate > 0.0f) ? 0.0f : d * d;
        }

        float part = block_reduce(acc);
        if (tid == 0) partials[blockIdx.x] = L_NOOBJ * part;  // plain store
    } else {
        // ---- bbox ordered-scan path (block 0, first dispatch round) ----
        __shared__ int s_wcnt[4];
        __shared__ int s_base;
        if (tid == 0) s_base = 0;
        __syncthreads();

        float local = 0.0f;
        for (int start = 0; start < M; start += 256) {
            int row = start + tid;
            bool obj = false;
            if (row < M) obj = ts[row * NCH + 4] > 0.0f;

            unsigned long long mask = __ballot(obj);
            int wid = tid >> 6;
            if (lane == 0) s_wcnt[wid] = __popcll(mask);
            __syncthreads();

            int base = s_base;
            int off = 0;
            for (int w = 0; w < wid; ++w) off += s_wcnt[w];
            int rank = base + off + __popcll(mask & ((1ULL << lane) - 1ULL));
            if (obj && rank < RANK_LIMIT) local += sel_loss(ps, ts, row);
            __syncthreads();

            if (tid == 0)
                s_base = base + s_wcnt[0] + s_wcnt[1] + s_wcnt[2] + s_wcnt[3];
            __syncthreads();
            if (s_base >= RANK_LIMIT) break;   // uniform exit
        }

        float part = block_reduce(local);
        if (tid == 0) partials[0] = part;      // plain store
    }
}

// ---------------------------------------------------------------------------
// Tiny finish kernel: sum the NB+1 partials (all already scaled) -> out[0].
// ---------------------------------------------------------------------------
__global__ __launch_bounds__(256) void sum_kernel(const float* __restrict__ partials,
                                                  float* __restrict__ out) {
    float v = 0.0f;
    for (int i = threadIdx.x; i < NBLK_TOTAL; i += 256)
        v += partials[i];
    float tot = block_reduce(v);
    if (threadIdx.x == 0) out[0] = tot;
}

extern "C" void kernel_launch(void* const* d_in, const int* in_sizes, int n_in,
                              void* d_out, int out_size, void* d_ws, size_t ws_size,
                              hipStream_t stream) {
    const float* pred = (const float*)d_in[0];
    const float* targ = (const float*)d_in[1];
    float* out = (float*)d_out;
    float* partials = (float*)d_ws;      // NB+1 floats; all written before read

    int M = in_sizes[0] / NCH;           // 802816 rows

    yolo_kernel<<<NBLK_TOTAL, 256, 0, stream>>>(pred, targ, partials, M);
    sum_kernel<<<1, 256, 0, stream>>>(partials, out);
}